// Round 5
// baseline (5380.360 us; speedup 1.0000x reference)
//
#include <hip/hip_runtime.h>
#include <hip/hip_bf16.h>

// Collapsed-projector persistent-GRU kernel for MI355X.
// Round 5: u-fold (projector folded into the recurrence via Wq = W_ih@Wp),
// out-projection moved off the critical path to wave 3 (deferred one step),
// publish-gated gather (no junk rounds). Tag-in-data sync as R4.

#define HIDDEN 1024
#define INDIM  63
#define TSEQ   512
#define MB     16
#define NGRP   4
#define HWORDS 512          // 8B words per h row (2 cols each)

typedef __attribute__((ext_vector_type(8))) short bfrag8;  // 8 bf16 in 4 VGPRs
typedef __attribute__((ext_vector_type(4))) float ffrag4;  // MFMA accumulator
typedef unsigned long long ull;

#define MFMA_B16(a, b, c) __builtin_amdgcn_mfma_f32_16x16x32_bf16((a), (b), (c), 0, 0, 0)

__device__ __forceinline__ short f2bf(float x) {
  __hip_bfloat16 b = __float2bfloat16(x);
  return __builtin_bit_cast(short, b);
}
__device__ __forceinline__ float bf2f(short s) {
  unsigned u = ((unsigned)(unsigned short)s) << 16;
  return __builtin_bit_cast(float, u);
}

// ---------------- precompute kernels (Wp = W3@W2@W1, bp) ----------------

__global__ void k_t1(const float* __restrict__ W2, const float* __restrict__ b1,
                     const float* __restrict__ b2, float* __restrict__ t1) {
  const int w = threadIdx.x >> 6, lane = threadIdx.x & 63;
  const int o = blockIdx.x * 4 + w;
  if (o >= HIDDEN) return;
  const float* row = W2 + (size_t)o * HIDDEN;
  float s = 0.f;
  for (int k = lane; k < HIDDEN; k += 64) s += row[k] * b1[k];
  for (int off = 32; off; off >>= 1) s += __shfl_down(s, off, 64);
  if (lane == 0) t1[o] = s + b2[o];
}

__global__ void k_bp(const float* __restrict__ W3, const float* __restrict__ t1,
                     const float* __restrict__ b3, float* __restrict__ bp) {
  const int w = threadIdx.x >> 6, lane = threadIdx.x & 63;
  for (int d = w; d < INDIM; d += 4) {
    const float* row = W3 + (size_t)d * HIDDEN;
    float s = 0.f;
    for (int k = lane; k < HIDDEN; k += 64) s += row[k] * t1[k];
    for (int off = 32; off; off >>= 1) s += __shfl_down(s, off, 64);
    if (lane == 0) bp[d] = s + b3[d];
  }
}

__global__ void k_gemm(const float* __restrict__ A, const float* __restrict__ B,
                       float* __restrict__ C, int M, int N, int K) {
  __shared__ float As[16][17], Bs[16][17];
  const int tx = threadIdx.x, ty = threadIdx.y;
  const int row = blockIdx.y * 16 + ty;
  const int col = blockIdx.x * 16 + tx;
  float acc = 0.f;
  for (int k0 = 0; k0 < K; k0 += 16) {
    As[ty][tx] = (row < M) ? A[(size_t)row * K + k0 + tx] : 0.f;
    Bs[ty][tx] = B[(size_t)(k0 + ty) * N + col];
    __syncthreads();
#pragma unroll
    for (int kk = 0; kk < 16; ++kk) acc += As[ty][kk] * Bs[kk][tx];
    __syncthreads();
  }
  if (row < M && col < N) C[(size_t)row * N + col] = acc;
}

// ---------------- main persistent kernel ----------------

__global__ __launch_bounds__(256, 1) void k_main(
    const float* __restrict__ X,
    const float* __restrict__ W_ih, const float* __restrict__ W_hh,
    const float* __restrict__ b_ih, const float* __restrict__ b_hh,
    const float* __restrict__ WpF, const float* __restrict__ bpF,
    const int* __restrict__ pCL, const int* __restrict__ pGT,
    ull* __restrict__ hb, float* __restrict__ OUT) {
  __shared__ short h_st[MB][HIDDEN + 8];   // staged h (also prologue scratch)
  __shared__ short inp_bf[MB][88];
  __shared__ float inp_f[MB][68];
  __shared__ float gt_z[MB][16], gt_un[MB][16], gt_ghn[MB][16];
  __shared__ float gt_xr[MB][16], gt_xz[MB][16], gt_xn[MB][16];
  __shared__ short htmp[MB][16];

  const int tid = threadIdx.x;
  const int w = tid >> 6;
  const int lane = tid & 63;
  const int c = lane & 15;
  const int quad = lane >> 4;
  const int g = blockIdx.x >> 6;
  const int j = blockIdx.x & 63;

  const int gtv = pGT[0];
  int period = pCL[0] + gtv;
  if (period < 1) period = 1;

  // --- persistent register-resident weight fragments ---
  bfrag8 wB[32];  // w<3: W_hh slice; w==3: [0..5] = W_ih slices
  bfrag8 wQ[32];  // w<3: Wq slice (built in prologue); w==3 & j<4: Wp out slice
  const int dd = 16 * j + c;  // out column (w3, j<4)
  const bool outw = (w == 3) && (j < 4);

  if (w < 3) {
    const float* wr = W_hh + ((size_t)w * HIDDEN + (size_t)j * 16 + c) * HIDDEN;
#pragma unroll
    for (int ks = 0; ks < 32; ++ks) {
      const float* p = wr + ks * 32 + quad * 8;
      bfrag8 f;
#pragma unroll
      for (int e = 0; e < 8; ++e) f[e] = f2bf(p[e]);
      wB[ks] = f;
    }
  } else {
#pragma unroll
    for (int gate = 0; gate < 3; ++gate) {
      const float* wr = W_ih + ((size_t)gate * HIDDEN + (size_t)j * 16 + c) * INDIM;
#pragma unroll
      for (int ks = 0; ks < 2; ++ks) {
        bfrag8 f;
#pragma unroll
        for (int e = 0; e < 8; ++e) {
          int k = ks * 32 + quad * 8 + e;
          f[e] = (k < INDIM) ? f2bf(wr[k]) : (short)0;
        }
        wB[gate * 2 + ks] = f;
      }
    }
    if (outw) {
      const float* wr = WpF + (size_t)dd * HIDDEN;
#pragma unroll
      for (int ks = 0; ks < 32; ++ks) {
        bfrag8 f;
#pragma unroll
        for (int e = 0; e < 8; ++e)
          f[e] = (dd < INDIM) ? f2bf(wr[ks * 32 + quad * 8 + e]) : (short)0;
        wQ[ks] = f;
      }
    }
  }

  float bias_g = 0.f, b_ihn_l = 0.f, bp_l = 0.f;
  if (w == 0) {
    bias_g = b_ih[j * 16 + c] + b_hh[j * 16 + c];
    b_ihn_l = b_ih[2 * HIDDEN + j * 16 + c];
  } else if (w == 1) bias_g = b_ih[HIDDEN + j * 16 + c] + b_hh[HIDDEN + j * 16 + c];
  else if (w == 2) bias_g = b_hh[2 * HIDDEN + j * 16 + c];
  else if (outw && dd < INDIM) bp_l = bpF[dd];

  // --- prologue: build Wq frags + bq in LDS scratch (overlays h_st) ---
  float bq_l = 0.f;
  {
    float* WihS = (float*)&h_st[0][0];        // [48][65] f32 = 12480 B
    float* WpS = WihS + 48 * 65;              // [63][33] f32 = 8316 B
    for (int i = tid; i < 48 * 63; i += 256) {
      int rw = i / 63, d = i - rw * 63;
      int r = (rw >> 4) * HIDDEN + j * 16 + (rw & 15);
      WihS[rw * 65 + d] = W_ih[(size_t)r * INDIM + d];
    }
    __syncthreads();
    if (w < 3) {
      const float* myrow = &WihS[(w * 16 + c) * 65];
      for (int d = 0; d < INDIM; ++d) bq_l += myrow[d] * bpF[d];
    }
    for (int ks = 0; ks < 32; ++ks) {
      __syncthreads();  // prior compute done before overwriting WpS
      for (int i = tid; i < 63 * 32; i += 256) {
        int d = i >> 5, kk = i & 31;
        WpS[d * 33 + kk] = WpF[(size_t)d * HIDDEN + ks * 32 + kk];
      }
      __syncthreads();
      if (w < 3) {
        const float* myrow = &WihS[(w * 16 + c) * 65];
        float acc[8] = {0, 0, 0, 0, 0, 0, 0, 0};
        for (int d = 0; d < INDIM; ++d) {
          float a = myrow[d];
          const float* pr = &WpS[d * 33 + quad * 8];
#pragma unroll
          for (int e = 0; e < 8; ++e) acc[e] += a * pr[e];
        }
        bfrag8 f;
#pragma unroll
        for (int e = 0; e < 8; ++e) f[e] = f2bf(acc[e]);
        wQ[ks] = f;
      }
    }
    __syncthreads();
  }

  // zero LDS state (h(-1)=0; inp pads must be 0 for u_x K-pad)
  for (int i = tid; i < MB * (HIDDEN + 8); i += 256) ((short*)h_st)[i] = 0;
  for (int i = tid; i < MB * 88; i += 256) ((short*)inp_bf)[i] = 0;
  for (int i = tid; i < MB * 68; i += 256) ((float*)inp_f)[i] = 0.f;

  ull* hb_g[2] = {hb + (size_t)g * MB * HWORDS,
                  hb + (size_t)(NGRP + g) * MB * HWORDS};

  ffrag4 up[4];  // persistent u parts (w<3)
#pragma unroll
  for (int p = 0; p < 4; ++p)
#pragma unroll
    for (int e = 0; e < 4; ++e) up[p][e] = 0.f;
  float inp_reg[4] = {0.f, 0.f, 0.f, 0.f};  // w3/j<4: inp(t) for its out cols

  for (int t = 0; t < TSEQ; ++t) {
    const unsigned tg = (unsigned)(t + 1);
    const bool teach = ((t % period) < gtv);
    if (teach) {
      const int row = tid >> 4, d0 = (tid & 15) * 4;
      const float* xr = X + ((size_t)(g * MB + row) * TSEQ + t) * INDIM;
#pragma unroll
      for (int e = 0; e < 4; ++e) {
        int d = d0 + e;
        float v = (d < INDIM) ? xr[d] : 0.f;
        inp_f[row][d] = v;
        inp_bf[row][d] = f2bf(v);
      }
    }
    __syncthreads();  // S1: inp ready; h_st holds h(t-1)

    ffrag4 ghr;
    float hp[4];
    if (w < 3) {
      ffrag4 acc[4];
#pragma unroll
      for (int e = 0; e < 4; ++e) {
        acc[0][e] = bias_g; acc[1][e] = 0.f; acc[2][e] = 0.f; acc[3][e] = 0.f;
      }
      const bool upd = !teach && (t > 0);  // u(t) = u(t-1) + h(t-1)@Wq + bq
      if (upd) {
#pragma unroll
        for (int ks = 0; ks < 32; ++ks) {
          const bfrag8 a = *(const bfrag8*)&h_st[c][ks * 32 + quad * 8];
          acc[ks & 3] = MFMA_B16(a, wB[ks], acc[ks & 3]);
          up[ks & 3] = MFMA_B16(a, wQ[ks], up[ks & 3]);
        }
#pragma unroll
        for (int e = 0; e < 4; ++e) up[0][e] += bq_l;
      } else {
#pragma unroll
        for (int ks = 0; ks < 32; ++ks) {
          const bfrag8 a = *(const bfrag8*)&h_st[c][ks * 32 + quad * 8];
          acc[ks & 3] = MFMA_B16(a, wB[ks], acc[ks & 3]);
        }
      }
      ffrag4 gsum = acc[0] + acc[1] + acc[2] + acc[3];
      if (w == 1) {
#pragma unroll
        for (int i = 0; i < 4; ++i) {
          float uz = teach ? 0.f : (up[0][i] + up[1][i] + up[2][i] + up[3][i]);
          gt_z[quad * 4 + i][c] = gsum[i] + uz;
        }
      } else if (w == 2) {
#pragma unroll
        for (int i = 0; i < 4; ++i) {
          gt_ghn[quad * 4 + i][c] = gsum[i];
          if (!teach)
            gt_un[quad * 4 + i][c] = up[0][i] + up[1][i] + up[2][i] + up[3][i];
        }
      } else {
        ghr = gsum;  // gh_r + biases; u_r added at gate time
#pragma unroll
        for (int i = 0; i < 4; ++i) hp[i] = bf2f(h_st[quad * 4 + i][j * 16 + c]);
      }
    } else {
      // wave 3: deferred out(t-1) (off critical path) + teach u_x tiles
      if (outw) {
        if (t > 0) {
          ffrag4 oa0, oa1;
#pragma unroll
          for (int e = 0; e < 4; ++e) { oa0[e] = bp_l; oa1[e] = 0.f; }
#pragma unroll
          for (int ks = 0; ks < 32; ++ks) {
            const bfrag8 a = *(const bfrag8*)&h_st[c][ks * 32 + quad * 8];
            if (ks & 1) oa1 = MFMA_B16(a, wQ[ks], oa1);
            else        oa0 = MFMA_B16(a, wQ[ks], oa0);
          }
          ffrag4 o = oa0 + oa1;
#pragma unroll
          for (int i = 0; i < 4; ++i) {
            const int row = quad * 4 + i;
            if (dd < INDIM) {
              float val = o[i] + inp_reg[i];
              OUT[((size_t)(g * MB + row) * TSEQ + (t - 1)) * INDIM + dd] = val;
              inp_reg[i] = teach ? inp_f[row][dd] : val;
            }
          }
        } else {
#pragma unroll
          for (int i = 0; i < 4; ++i)
            if (dd < INDIM)
              inp_reg[i] = teach ? inp_f[quad * 4 + i][dd] : 0.f;
        }
      }
      if (teach) {
        ffrag4 xr, xz, xn;
#pragma unroll
        for (int e = 0; e < 4; ++e) { xr[e] = 0.f; xz[e] = 0.f; xn[e] = 0.f; }
#pragma unroll
        for (int ks = 0; ks < 2; ++ks) {
          const bfrag8 a = *(const bfrag8*)&inp_bf[c][ks * 32 + quad * 8];
          xr = MFMA_B16(a, wB[0 + ks], xr);
          xz = MFMA_B16(a, wB[2 + ks], xz);
          xn = MFMA_B16(a, wB[4 + ks], xn);
        }
#pragma unroll
        for (int i = 0; i < 4; ++i) {
          gt_xr[quad * 4 + i][c] = xr[i];
          gt_xz[quad * 4 + i][c] = xz[i];
          gt_xn[quad * 4 + i][c] = xn[i];
        }
      }
    }
    __syncthreads();  // S2: tiles ready

    ull* hw = hb_g[t & 1];
    if (w == 0) {
#pragma unroll
      for (int i = 0; i < 4; ++i) {
        const int row = quad * 4 + i;
        float ur = teach ? gt_xr[row][c]
                         : (up[0][i] + up[1][i] + up[2][i] + up[3][i]);
        float r = 1.f / (1.f + __expf(-(ghr[i] + ur)));
        float zt = gt_z[row][c] + (teach ? gt_xz[row][c] : 0.f);
        float z = 1.f / (1.f + __expf(-zt));
        float un = teach ? gt_xn[row][c] : gt_un[row][c];
        float n = tanhf(un + b_ihn_l + r * gt_ghn[row][c]);
        htmp[row][c] = f2bf((1.f - z) * n + z * hp[i]);
      }
      asm volatile("" ::: "memory");  // TBAA-safe: keep reads below stores
      const int r = lane >> 2, q4 = (lane & 3) * 4;
      unsigned lo0 = (unsigned)(unsigned short)htmp[r][q4 + 0] |
                     ((unsigned)(unsigned short)htmp[r][q4 + 1] << 16);
      unsigned lo1 = (unsigned)(unsigned short)htmp[r][q4 + 2] |
                     ((unsigned)(unsigned short)htmp[r][q4 + 3] << 16);
      ull w0v = ((ull)tg << 32) | lo0;
      ull w1v = ((ull)tg << 32) | lo1;
      ull* dst = hw + (size_t)r * HWORDS + 8 * j + (lane & 3) * 2;
      __hip_atomic_store(dst, w0v, __ATOMIC_RELAXED, __HIP_MEMORY_SCOPE_SYSTEM);
      __hip_atomic_store(dst + 1, w1v, __ATOMIC_RELAXED, __HIP_MEMORY_SCOPE_SYSTEM);
    }
    // teach: reset u parts to u_x (post-S2 tile read)
    if (teach && w < 3) {
#pragma unroll
      for (int i = 0; i < 4; ++i) {
        float v = (w == 0) ? gt_xr[quad * 4 + i][c]
                : (w == 1) ? gt_xz[quad * 4 + i][c]
                           : gt_xn[quad * 4 + i][c];
        up[0][i] = v; up[1][i] = 0.f; up[2][i] = 0.f; up[3][i] = 0.f;
      }
    }
    __syncthreads();  // S2b: gate gather on publish (kills junk rounds)

    {  // gather h(t): the load IS the barrier — retry words until tag == t+1
      ull v[32];
#pragma unroll
      for (int s = 0; s < 32; ++s)
        v[s] = __hip_atomic_load(&hw[tid + s * 256], __ATOMIC_RELAXED,
                                 __HIP_MEMORY_SCOPE_SYSTEM);
      bool bad = true;
      while (bad) {
        bad = false;
#pragma unroll
        for (int s = 0; s < 32; ++s) {
          if ((unsigned)(v[s] >> 32) != tg) {
            v[s] = __hip_atomic_load(&hw[tid + s * 256], __ATOMIC_RELAXED,
                                     __HIP_MEMORY_SCOPE_SYSTEM);
            bad = true;
          }
        }
      }
#pragma unroll
      for (int s = 0; s < 32; ++s) {
        const int widx = tid + s * 256;          // 16 rows x 512 words
        *(unsigned*)&h_st[widx >> 9][(widx & 511) * 2] = (unsigned)v[s];
      }
    }
    __syncthreads();  // S3: h_st = h(t)
  }

  // epilogue: out(TSEQ-1) from final h_st
  if (outw) {
    ffrag4 oa0, oa1;
#pragma unroll
    for (int e = 0; e < 4; ++e) { oa0[e] = bp_l; oa1[e] = 0.f; }
#pragma unroll
    for (int ks = 0; ks < 32; ++ks) {
      const bfrag8 a = *(const bfrag8*)&h_st[c][ks * 32 + quad * 8];
      if (ks & 1) oa1 = MFMA_B16(a, wQ[ks], oa1);
      else        oa0 = MFMA_B16(a, wQ[ks], oa0);
    }
    ffrag4 o = oa0 + oa1;
#pragma unroll
    for (int i = 0; i < 4; ++i) {
      const int row = quad * 4 + i;
      if (dd < INDIM)
        OUT[((size_t)(g * MB + row) * TSEQ + (TSEQ - 1)) * INDIM + dd] =
            o[i] + inp_reg[i];
    }
  }
}

// ---------------- host ----------------

extern "C" void kernel_launch(void* const* d_in, const int* in_sizes, int n_in,
                              void* d_out, int out_size, void* d_ws, size_t ws_size,
                              hipStream_t stream) {
  const float* X    = (const float*)d_in[0];
  const float* W_ih = (const float*)d_in[1];
  const float* W_hh = (const float*)d_in[2];
  const float* b_ih = (const float*)d_in[3];
  const float* b_hh = (const float*)d_in[4];
  const float* W1   = (const float*)d_in[5];
  const float* b1   = (const float*)d_in[6];
  const float* W2   = (const float*)d_in[7];
  const float* b2   = (const float*)d_in[8];
  const float* W3   = (const float*)d_in[9];
  const float* b3   = (const float*)d_in[10];
  const int* pCL    = (const int*)d_in[11];
  const int* pGT    = (const int*)d_in[12];
  float* OUT = (float*)d_out;

  // layout: T2 aliases hb (dead before k_main; hb memset after)
  char* ws = (char*)d_ws;
  float* bp = (float*)(ws + 1024);        // 63 f32
  float* t1 = (float*)(ws + 2048);        // 1024 f32
  float* Wp = (float*)(ws + 8192);        // 63x1024 f32 (258048 B)
  float* T2 = (float*)(ws + 270336);      // 63x1024 f32 scratch (aliases hb)
  ull*   hb = (ull*)(ws + 270336);        // 2 x 4 x 16 x 512 ull = 512 KB
  if (ws_size < 795 * 1024) return;

  k_t1<<<256, 256, 0, stream>>>(W2, b1, b2, t1);
  k_gemm<<<dim3(64, 4), dim3(16, 16), 0, stream>>>(W3, W2, T2, INDIM, HIDDEN, HIDDEN);
  k_gemm<<<dim3(64, 4), dim3(16, 16), 0, stream>>>(T2, W1, Wp, INDIM, HIDDEN, HIDDEN);
  k_bp<<<1, 256, 0, stream>>>(W3, t1, b3, bp);
  hipMemsetAsync(hb, 0, 2 * NGRP * MB * HWORDS * sizeof(ull), stream);  // tags := 0
  k_main<<<256, 256, 0, stream>>>(X, W_ih, W_hh, b_ih, b_hh, Wp, bp, pCL, pGT, hb, OUT);
}

// Round 6
// 3457.338 us; speedup vs baseline: 1.5562x; 1.5562x over previous
//
#include <hip/hip_runtime.h>
#include <hip/hip_bf16.h>

// Collapsed-projector persistent-GRU kernel for MI355X.
// Round 6 = Round 4 (proven 3.81 ms) + LDS publish-issue gate:
// waves 1-3 delay gather issue until w0 has ISSUED its tagged publish
// stores (LDS flag, no vmcnt drain, no barrier). Tags remain the sole
// correctness mechanism; the gate only removes the guaranteed-junk
// first gather round.

#define HIDDEN 1024
#define INDIM  63
#define TSEQ   512
#define MB     16
#define NGRP   4
#define HWORDS 512          // 8B words per h row (2 cols each)

typedef __attribute__((ext_vector_type(8))) short bfrag8;  // 8 bf16 in 4 VGPRs
typedef __attribute__((ext_vector_type(4))) float ffrag4;  // MFMA accumulator
typedef unsigned long long ull;

#define MFMA_B16(a, b, c) __builtin_amdgcn_mfma_f32_16x16x32_bf16((a), (b), (c), 0, 0, 0)

__device__ __forceinline__ short f2bf(float x) {
  __hip_bfloat16 b = __float2bfloat16(x);
  return __builtin_bit_cast(short, b);
}
__device__ __forceinline__ float bf2f(short s) {
  unsigned u = ((unsigned)(unsigned short)s) << 16;
  return __builtin_bit_cast(float, u);
}

// ---------------- precompute kernels ----------------

__global__ void k_t1(const float* __restrict__ W2, const float* __restrict__ b1,
                     const float* __restrict__ b2, float* __restrict__ t1) {
  const int w = threadIdx.x >> 6, lane = threadIdx.x & 63;
  const int o = blockIdx.x * 4 + w;
  if (o >= HIDDEN) return;
  const float* row = W2 + (size_t)o * HIDDEN;
  float s = 0.f;
  for (int k = lane; k < HIDDEN; k += 64) s += row[k] * b1[k];
  for (int off = 32; off; off >>= 1) s += __shfl_down(s, off, 64);
  if (lane == 0) t1[o] = s + b2[o];
}

__global__ void k_bp(const float* __restrict__ W3, const float* __restrict__ t1,
                     const float* __restrict__ b3, float* __restrict__ bp) {
  const int w = threadIdx.x >> 6, lane = threadIdx.x & 63;
  for (int d = w; d < INDIM; d += 4) {
    const float* row = W3 + (size_t)d * HIDDEN;
    float s = 0.f;
    for (int k = lane; k < HIDDEN; k += 64) s += row[k] * t1[k];
    for (int off = 32; off; off >>= 1) s += __shfl_down(s, off, 64);
    if (lane == 0) bp[d] = s + b3[d];
  }
}

__global__ void k_gemm(const float* __restrict__ A, const float* __restrict__ B,
                       float* __restrict__ C, int M, int N, int K) {
  __shared__ float As[16][17], Bs[16][17];
  const int tx = threadIdx.x, ty = threadIdx.y;
  const int row = blockIdx.y * 16 + ty;
  const int col = blockIdx.x * 16 + tx;
  float acc = 0.f;
  for (int k0 = 0; k0 < K; k0 += 16) {
    As[ty][tx] = (row < M) ? A[(size_t)row * K + k0 + tx] : 0.f;
    Bs[ty][tx] = B[(size_t)(k0 + ty) * N + col];
    __syncthreads();
#pragma unroll
    for (int kk = 0; kk < 16; ++kk) acc += As[ty][kk] * Bs[kk][tx];
    __syncthreads();
  }
  if (row < M && col < N) C[(size_t)row * N + col] = acc;
}

// ---------------- main persistent kernel ----------------

__global__ __launch_bounds__(256, 1) void k_main(
    const float* __restrict__ X,
    const float* __restrict__ W_ih, const float* __restrict__ W_hh,
    const float* __restrict__ b_ih, const float* __restrict__ b_hh,
    const float* __restrict__ WpF, const float* __restrict__ bpF,
    const int* __restrict__ pCL, const int* __restrict__ pGT,
    ull* __restrict__ hb, float* __restrict__ OUT) {
  __shared__ short h_st[MB][HIDDEN + 8];   // staged h, row stride 2064B
  __shared__ short inp_bf[MB][88];
  __shared__ float inp_f[MB][68];
  __shared__ float gt_z[MB][16], gt_hn[MB][16];
  __shared__ float gt_ir[MB][16], gt_iz[MB][16], gt_in[MB][16];
  __shared__ short htmp[MB][16];           // h-slice repack for packed store
  __shared__ int pub_flag;                 // publish-issue gate (perf only)

  const int tid = threadIdx.x;
  const int w = tid >> 6;
  const int lane = tid & 63;
  const int c = lane & 15;
  const int quad = lane >> 4;
  const int g = blockIdx.x >> 6;
  const int j = blockIdx.x & 63;

  const int gtv = pGT[0];
  int period = pCL[0] + gtv;
  if (period < 1) period = 1;

  // --- persistent register-resident weight fragments ---
  bfrag8 wB[32];
  bfrag8 wp[32];
  if (w < 3) {
    const float* wr = W_hh + ((size_t)w * HIDDEN + (size_t)j * 16 + c) * HIDDEN;
#pragma unroll
    for (int ks = 0; ks < 32; ++ks) {
      const float* p = wr + ks * 32 + quad * 8;
      bfrag8 f;
#pragma unroll
      for (int e = 0; e < 8; ++e) f[e] = f2bf(p[e]);
      wB[ks] = f;
    }
  } else {
#pragma unroll
    for (int gate = 0; gate < 3; ++gate) {
      const float* wr = W_ih + ((size_t)gate * HIDDEN + (size_t)j * 16 + c) * INDIM;
#pragma unroll
      for (int ks = 0; ks < 2; ++ks) {
        bfrag8 f;
#pragma unroll
        for (int e = 0; e < 8; ++e) {
          int k = ks * 32 + quad * 8 + e;
          f[e] = (k < INDIM) ? f2bf(wr[k]) : (short)0;
        }
        wB[gate * 2 + ks] = f;
      }
    }
  }
  const int dd = 16 * w + c;
  {
    const float* wr = WpF + (size_t)dd * HIDDEN;
#pragma unroll
    for (int ks = 0; ks < 32; ++ks) {
      bfrag8 f;
#pragma unroll
      for (int e = 0; e < 8; ++e)
        f[e] = (dd < INDIM) ? f2bf(wr[ks * 32 + quad * 8 + e]) : (short)0;
      wp[ks] = f;
    }
  }

  float bias_g;
  if (w == 0)      bias_g = b_ih[j * 16 + c] + b_hh[j * 16 + c];
  else if (w == 1) bias_g = b_ih[HIDDEN + j * 16 + c] + b_hh[HIDDEN + j * 16 + c];
  else if (w == 2) bias_g = b_hh[2 * HIDDEN + j * 16 + c];
  else             bias_g = b_ih[2 * HIDDEN + j * 16 + c];
  const float bp_l = (dd < INDIM) ? bpF[dd] : 0.f;

  for (int i = tid; i < MB * (HIDDEN + 8); i += 256) ((short*)h_st)[i] = 0;
  for (int i = tid; i < MB * 88; i += 256) ((short*)inp_bf)[i] = 0;
  for (int i = tid; i < MB * 68; i += 256) ((float*)inp_f)[i] = 0.f;
  if (tid == 0) pub_flag = 0;

  // tagged h buffers: [2][NGRP][MB][HWORDS] ull
  ull* hb_g[2] = {hb + (size_t)g * MB * HWORDS,
                  hb + (size_t)(NGRP + g) * MB * HWORDS};

  for (int t = 0; t < TSEQ; ++t) {
    const unsigned tg = (unsigned)(t + 1);
    const bool teach = ((t % period) < gtv);
    if (teach) {
      const int row = tid >> 4, d0 = (tid & 15) * 4;
      const float* xr = X + ((size_t)(g * MB + row) * TSEQ + t) * INDIM;
#pragma unroll
      for (int e = 0; e < 4; ++e) {
        int d = d0 + e;
        float v = (d < INDIM) ? xr[d] : 0.f;
        inp_f[row][d] = v;
        inp_bf[row][d] = f2bf(v);
      }
    }
    __syncthreads();  // S1: inp ready; h_st holds h(t-1)

    ffrag4 ghr;
    float hp[4];  // w0 snapshots h_prev before gather overwrites h_st
    if (w < 3) {
      ffrag4 acc[4];
#pragma unroll
      for (int e = 0; e < 4; ++e) {
        acc[0][e] = bias_g; acc[1][e] = 0.f; acc[2][e] = 0.f; acc[3][e] = 0.f;
      }
#pragma unroll
      for (int ks = 0; ks < 32; ++ks) {
        const bfrag8 a = *(const bfrag8*)&h_st[c][ks * 32 + quad * 8];
        acc[ks & 3] = MFMA_B16(a, wB[ks], acc[ks & 3]);
      }
      ffrag4 gsum = acc[0] + acc[1] + acc[2] + acc[3];
      if (w == 1) {
#pragma unroll
        for (int i = 0; i < 4; ++i) gt_z[quad * 4 + i][c] = gsum[i];
      } else if (w == 2) {
#pragma unroll
        for (int i = 0; i < 4; ++i) gt_hn[quad * 4 + i][c] = gsum[i];
      } else {
        ghr = gsum;
#pragma unroll
        for (int i = 0; i < 4; ++i) hp[i] = bf2f(h_st[quad * 4 + i][j * 16 + c]);
      }
    } else {
      ffrag4 gir, giz, gin;
#pragma unroll
      for (int e = 0; e < 4; ++e) { gir[e] = 0.f; giz[e] = 0.f; gin[e] = bias_g; }
#pragma unroll
      for (int ks = 0; ks < 2; ++ks) {
        const bfrag8 a = *(const bfrag8*)&inp_bf[c][ks * 32 + quad * 8];
        gir = MFMA_B16(a, wB[0 + ks], gir);
        giz = MFMA_B16(a, wB[2 + ks], giz);
        gin = MFMA_B16(a, wB[4 + ks], gin);
      }
#pragma unroll
      for (int i = 0; i < 4; ++i) {
        gt_ir[quad * 4 + i][c] = gir[i];
        gt_iz[quad * 4 + i][c] = giz[i];
        gt_in[quad * 4 + i][c] = gin[i];
      }
    }
    __syncthreads();  // S2: gate tiles ready; h_st now dead until gather refill

    ull* hw = hb_g[t & 1];
    if (w == 0) {
      // gates -> h_new (bf16) -> htmp (wave-local repack) -> tagged publish
#pragma unroll
      for (int i = 0; i < 4; ++i) {
        const int row = quad * 4 + i;
        float r = 1.f / (1.f + __expf(-(ghr[i] + gt_ir[row][c])));
        float z = 1.f / (1.f + __expf(-(gt_z[row][c] + gt_iz[row][c])));
        float n = tanhf(gt_in[row][c] + r * gt_hn[row][c]);
        htmp[row][c] = f2bf((1.f - z) * n + z * hp[i]);
      }
      // TBAA-safe repack: same-typed (short) loads + compiler memory fence so
      // the reads can never be scheduled above the htmp stores.
      asm volatile("" ::: "memory");
      const int r = lane >> 2, q4 = (lane & 3) * 4;   // 4 cols = 2 words per lane
      unsigned lo0 = (unsigned)(unsigned short)htmp[r][q4 + 0] |
                     ((unsigned)(unsigned short)htmp[r][q4 + 1] << 16);
      unsigned lo1 = (unsigned)(unsigned short)htmp[r][q4 + 2] |
                     ((unsigned)(unsigned short)htmp[r][q4 + 3] << 16);
      ull w0v = ((ull)tg << 32) | lo0;
      ull w1v = ((ull)tg << 32) | lo1;
      ull* dst = hw + (size_t)r * HWORDS + 8 * j + (lane & 3) * 2;
      __hip_atomic_store(dst, w0v, __ATOMIC_RELAXED, __HIP_MEMORY_SCOPE_SYSTEM);
      __hip_atomic_store(dst + 1, w1v, __ATOMIC_RELAXED, __HIP_MEMORY_SCOPE_SYSTEM);
      // open the gather gate AFTER the publish stores are issued (no drain).
      asm volatile("" ::: "memory");
      if (lane == 0) *(volatile int*)&pub_flag = (int)tg;
    } else {
      // perf-only gate: wait until w0 has issued its publish (LDS spin,
      // no fabric traffic). Correctness is still carried by the tags.
      while (*(volatile int*)&pub_flag < (int)tg) __builtin_amdgcn_s_sleep(1);
    }

    // gather h(t): the load IS the barrier — retry words until tag == t+1
    {
      ull v[32];
#pragma unroll
      for (int s = 0; s < 32; ++s)
        v[s] = __hip_atomic_load(&hw[tid + s * 256], __ATOMIC_RELAXED,
                                 __HIP_MEMORY_SCOPE_SYSTEM);
      bool bad = true;
      while (bad) {
        bad = false;
#pragma unroll
        for (int s = 0; s < 32; ++s) {
          if ((unsigned)(v[s] >> 32) != tg) {
            v[s] = __hip_atomic_load(&hw[tid + s * 256], __ATOMIC_RELAXED,
                                     __HIP_MEMORY_SCOPE_SYSTEM);
            bad = true;
          }
        }
      }
#pragma unroll
      for (int s = 0; s < 32; ++s) {
        const int widx = tid + s * 256;          // 16 rows x 512 words
        *(unsigned*)&h_st[widx >> 9][(widx & 511) * 2] = (unsigned)v[s];
      }
    }
    __syncthreads();  // S3: h_st = h(t)

    // out(t) = inp(t) + h(t) @ Wp^T + bp
    const bool rep = (t + 1 < TSEQ) && !(((t + 1) % period) < gtv);
    if (rep || j == 0) {
      ffrag4 oa0, oa1;
#pragma unroll
      for (int e = 0; e < 4; ++e) { oa0[e] = bp_l; oa1[e] = 0.f; }
#pragma unroll
      for (int ks = 0; ks < 32; ++ks) {
        const bfrag8 a = *(const bfrag8*)&h_st[c][ks * 32 + quad * 8];
        if (ks & 1) oa1 = MFMA_B16(a, wp[ks], oa1);
        else        oa0 = MFMA_B16(a, wp[ks], oa0);
      }
      ffrag4 o = oa0 + oa1;
#pragma unroll
      for (int i = 0; i < 4; ++i) {
        const int row = quad * 4 + i;
        if (dd < INDIM) {
          float val = o[i] + inp_f[row][dd];
          if (j == 0) OUT[((size_t)(g * MB + row) * TSEQ + t) * INDIM + dd] = val;
          if (rep) { inp_f[row][dd] = val; inp_bf[row][dd] = f2bf(val); }
        } else if (rep) {
          inp_bf[row][dd] = 0;
        }
      }
    }
    // loop-head S1 orders inp writes vs next gi reads
  }
}

// ---------------- host ----------------

extern "C" void kernel_launch(void* const* d_in, const int* in_sizes, int n_in,
                              void* d_out, int out_size, void* d_ws, size_t ws_size,
                              hipStream_t stream) {
  const float* X    = (const float*)d_in[0];
  const float* W_ih = (const float*)d_in[1];
  const float* W_hh = (const float*)d_in[2];
  const float* b_ih = (const float*)d_in[3];
  const float* b_hh = (const float*)d_in[4];
  const float* W1   = (const float*)d_in[5];
  const float* b1   = (const float*)d_in[6];
  const float* W2   = (const float*)d_in[7];
  const float* b2   = (const float*)d_in[8];
  const float* W3   = (const float*)d_in[9];
  const float* b3   = (const float*)d_in[10];
  const int* pCL    = (const int*)d_in[11];
  const int* pGT    = (const int*)d_in[12];
  float* OUT = (float*)d_out;

  // layout: T2 aliases hb (dead before k_main; hb memset after)
  char* ws = (char*)d_ws;
  float* bp = (float*)(ws + 1024);        // 63 f32
  float* t1 = (float*)(ws + 2048);        // 1024 f32
  float* Wp = (float*)(ws + 8192);        // 63x1024 f32 (258048 B)
  float* T2 = (float*)(ws + 270336);      // 63x1024 f32 scratch (aliases hb)
  ull*   hb = (ull*)(ws + 270336);        // 2 x 4 x 16 x 512 ull = 512 KB
  if (ws_size < 795 * 1024) return;

  k_t1<<<256, 256, 0, stream>>>(W2, b1, b2, t1);
  k_gemm<<<dim3(64, 4), dim3(16, 16), 0, stream>>>(W3, W2, T2, INDIM, HIDDEN, HIDDEN);
  k_gemm<<<dim3(64, 4), dim3(16, 16), 0, stream>>>(T2, W1, Wp, INDIM, HIDDEN, HIDDEN);
  k_bp<<<1, 256, 0, stream>>>(W3, t1, b3, bp);
  hipMemsetAsync(hb, 0, 2 * NGRP * MB * HWORDS * sizeof(ull), stream);  // tags := 0
  k_main<<<256, 256, 0, stream>>>(X, W_ih, W_hh, b_ih, b_hh, Wp, bp, pCL, pGT, hb, OUT);
}